// Round 1
// baseline (901.932 us; speedup 1.0000x reference)
//
#include <hip/hip_runtime.h>

// out[b,i,e] = x[b,i] * W[i,e] + bias[i,e]
// B=16384, N_NUM=200, EMB=64. Output fp32, 839 MB -> HBM-write-bound.

#define N_NUM 200
#define EMB 64
#define ROW_F4 (N_NUM * EMB / 4) /* 3200 float4 per batch row */
#define BLOCK 320                /* 5 waves; 3200/320 = 10 exact iters */

__global__ __launch_bounds__(BLOCK) void numproj_kernel(
    const float* __restrict__ x,
    const float4* __restrict__ W4,
    const float4* __restrict__ b4,
    float4* __restrict__ out4) {
    const int b = blockIdx.x; // 0..16383
    const float* xrow = x + b * N_NUM;
    float4* orow = out4 + (size_t)b * ROW_F4;

#pragma unroll
    for (int k = 0; k < 10; ++k) {
        const int j = k * BLOCK + (int)threadIdx.x; // 0..3199, float4 index in row
        const int i = j >> 4;                       // feature index (16 float4 per feature)
        const float xv = xrow[i];                   // shared by 16 consecutive lanes (L1 broadcast)
        const float4 w = W4[j];                     // j == i*16 + q, exact flat index into W
        const float4 bb = b4[j];
        float4 o;
        o.x = fmaf(xv, w.x, bb.x);
        o.y = fmaf(xv, w.y, bb.y);
        o.z = fmaf(xv, w.z, bb.z);
        o.w = fmaf(xv, w.w, bb.w);
        orow[j] = o; // fully coalesced 16B/lane stores
    }
}

extern "C" void kernel_launch(void* const* d_in, const int* in_sizes, int n_in,
                              void* d_out, int out_size, void* d_ws, size_t ws_size,
                              hipStream_t stream) {
    const float* x = (const float*)d_in[0];
    const float4* W4 = (const float4*)d_in[1];
    const float4* b4 = (const float4*)d_in[2];
    float4* out4 = (float4*)d_out;

    const int batch = in_sizes[0] / N_NUM; // 16384
    numproj_kernel<<<batch, BLOCK, 0, stream>>>(x, W4, b4, out4);
}